// Round 2
// baseline (199.513 us; speedup 1.0000x reference)
//
#include <hip/hip_runtime.h>
#include <math.h>

#define NN 100000
#define NE 500000

// ---------------------------------------------------------------------------
// Kernel 1: per-node projection.
//   AB[n][0:64]   = h[n] @ W1[0:128, :]   + b1      (source-role, b1 folded)
//   AB[n][64:128] = h[n] @ W1[128:256, :]           (target-role)
// Treated as one GEMM: M=100000, K=128, Nout=128 with merged weight
//   Wc[k][j] = (j<64) ? W1[k][j] : W1[128+k][j-64]
// 256 threads/block, 128 nodes/block, per-lane 8 nodes x 8 outputs.
// K-chunk = 32  ->  LDS = 16KB (W) + 18KB (h) = 34KB -> 4 blocks/CU.
// ---------------------------------------------------------------------------
__global__ __launch_bounds__(256, 4)
void node_proj(const float* __restrict__ h, const float* __restrict__ W1,
               const float* __restrict__ b1, float* __restrict__ AB, int nnodes)
{
    __shared__ float lw[32 * 128];     // 16 KB: 32 k-rows x 128 outputs
    __shared__ float lh[128 * 36];     // 18 KB: 128 nodes x 32 k, stride 36 (36%32==4 -> conflict-free reads)

    const int t   = threadIdx.x;
    const int tj  = t & 15;      // output group: j = 4*tj (A-half) and 64+4*tj (B-half)
    const int tnf = t >> 4;      // node group:  rows tnf + 16*r, r=0..7
    const int n0  = blockIdx.x * 128;

    float acc[8][8];
#pragma unroll
    for (int r = 0; r < 8; ++r)
#pragma unroll
        for (int j = 0; j < 8; ++j) acc[r][j] = 0.f;

    for (int kc = 0; kc < 4; ++kc) {
        // ---- stage Wc chunk: 32 rows x 128 outputs (1024 float4, 4/thread) ----
#pragma unroll
        for (int i = 0; i < 4; ++i) {
            int cid = t + 256 * i;        // 0..1023
            int kl  = cid >> 5;           // 0..31
            int q   = cid & 31;           // float4 index within row
            int jo  = q * 4;
            int kg  = kc * 32 + kl;
            const float* src = (jo < 64) ? (W1 + kg * 64 + jo)
                                         : (W1 + (128 + kg) * 64 + (jo - 64));
            float4 v = *(const float4*)src;
            *(float4*)&lw[kl * 128 + jo] = v;
        }
        // ---- stage h tile: 128 nodes x 32 k (1024 float4, 4/thread) ----
#pragma unroll
        for (int i = 0; i < 4; ++i) {
            int cid = t + 256 * i;        // 0..1023
            int nl  = cid >> 3;           // 0..127
            int kq  = cid & 7;            // 8 float4 per node-row chunk
            int ng  = n0 + nl;
            float4 v = make_float4(0.f, 0.f, 0.f, 0.f);
            if (ng < nnodes) v = *(const float4*)&h[ng * 128 + kc * 32 + kq * 4];
            *(float4*)&lh[nl * 36 + kq * 4] = v;
        }
        __syncthreads();

        // ---- FMA inner loop over this K-chunk (8 k4 iterations) ----
#pragma unroll
        for (int k4 = 0; k4 < 8; ++k4) {
            float hv[8][4];
#pragma unroll
            for (int r = 0; r < 8; ++r) {
                float4 x = *(const float4*)&lh[(tnf + 16 * r) * 36 + k4 * 4];
                hv[r][0] = x.x; hv[r][1] = x.y; hv[r][2] = x.z; hv[r][3] = x.w;
            }
#pragma unroll
            for (int kk = 0; kk < 4; ++kk) {
                float4 wa = *(const float4*)&lw[(k4 * 4 + kk) * 128 + tj * 4];
                float4 wb = *(const float4*)&lw[(k4 * 4 + kk) * 128 + 64 + tj * 4];
#pragma unroll
                for (int r = 0; r < 8; ++r) {
                    float hval = hv[r][kk];
                    acc[r][0] += hval * wa.x;
                    acc[r][1] += hval * wa.y;
                    acc[r][2] += hval * wa.z;
                    acc[r][3] += hval * wa.w;
                    acc[r][4] += hval * wb.x;
                    acc[r][5] += hval * wb.y;
                    acc[r][6] += hval * wb.z;
                    acc[r][7] += hval * wb.w;
                }
            }
        }
        __syncthreads();
    }

    // ---- epilogue: add b1 to the A-half, store both halves ----
    float4 bva = *(const float4*)&b1[tj * 4];
#pragma unroll
    for (int r = 0; r < 8; ++r) {
        int ng = n0 + tnf + 16 * r;
        if (ng >= nnodes) continue;
        float4 o1 = make_float4(acc[r][0] + bva.x, acc[r][1] + bva.y,
                                acc[r][2] + bva.z, acc[r][3] + bva.w);
        float4 o2 = make_float4(acc[r][4], acc[r][5], acc[r][6], acc[r][7]);
        *(float4*)&AB[ng * 128 + tj * 4]      = o1;   // A-half: outputs 4*tj..
        *(float4*)&AB[ng * 128 + 64 + tj * 4] = o2;   // B-half: outputs 64+4*tj..
    }
}

// ---------------------------------------------------------------------------
// Kernel 2: per-edge sample. 16 lanes per edge; lane l owns hid[4l..4l+3].
// hid = relu(AB[row][0:64] + AB[col][64:128])   (b1 already folded into A)
// logits = hid @ W2 + b2 ;  weight = (logits + g1 > g0) ? 1 : 0
// ---------------------------------------------------------------------------
__global__ __launch_bounds__(256)
void edge_sample(const float* __restrict__ AB, const float* __restrict__ W2,
                 const float* __restrict__ b2, const float* __restrict__ u,
                 const int* __restrict__ ei, float* __restrict__ out)
{
    int t = threadIdx.x;
    int l = t & 15;
    int e = blockIdx.x * 16 + (t >> 4);

    int row = ei[e];
    int col = ei[NE + e];

    float4 a = *(const float4*)&AB[row * 128 + l * 4];
    float4 b = *(const float4*)&AB[col * 128 + 64 + l * 4];
    float4 w = *(const float4*)&W2[l * 4];

    float h0 = fmaxf(a.x + b.x, 0.f);
    float h1 = fmaxf(a.y + b.y, 0.f);
    float h2 = fmaxf(a.z + b.z, 0.f);
    float h3 = fmaxf(a.w + b.w, 0.f);

    float p = h0 * w.x + h1 * w.y + h2 * w.z + h3 * w.w;
    p += __shfl_xor(p, 1);
    p += __shfl_xor(p, 2);
    p += __shfl_xor(p, 4);
    p += __shfl_xor(p, 8);

    if (l == 0) {
        float logit = p + b2[0];
        float u0 = u[2 * e];
        float u1 = u[2 * e + 1];
        float g0 = -logf(-logf(u0));
        float g1 = -logf(-logf(u1));
        out[e]      = (logit + g1 > g0) ? 1.0f : 0.0f;  // argmax tie -> 0
        out[NE + e] = logit;
    }
}

// ---------------------------------------------------------------------------
// Fallback (only if ws_size too small): direct per-edge compute, correct but slow.
// ---------------------------------------------------------------------------
__global__ __launch_bounds__(256)
void edge_direct(const float* __restrict__ h, const float* __restrict__ W1,
                 const float* __restrict__ b1, const float* __restrict__ W2,
                 const float* __restrict__ b2, const float* __restrict__ u,
                 const int* __restrict__ ei, float* __restrict__ out)
{
    int t = threadIdx.x;
    int l = t & 15;
    int e = blockIdx.x * 16 + (t >> 4);

    int row = ei[e];
    int col = ei[NE + e];

    float a0 = 0.f, a1 = 0.f, a2 = 0.f, a3 = 0.f;
    const float* hr = h + (size_t)row * 128;
    const float* hc = h + (size_t)col * 128;

    for (int k4 = 0; k4 < 32; ++k4) {
        float4 hv = *(const float4*)&hr[k4 * 4];
#pragma unroll
        for (int kk = 0; kk < 4; ++kk) {
            float4 wr = *(const float4*)&W1[(k4 * 4 + kk) * 64 + l * 4];
            float hval = (&hv.x)[kk];
            a0 += hval * wr.x; a1 += hval * wr.y; a2 += hval * wr.z; a3 += hval * wr.w;
        }
    }
    for (int k4 = 0; k4 < 32; ++k4) {
        float4 hv = *(const float4*)&hc[k4 * 4];
#pragma unroll
        for (int kk = 0; kk < 4; ++kk) {
            float4 wr = *(const float4*)&W1[(128 + k4 * 4 + kk) * 64 + l * 4];
            float hval = (&hv.x)[kk];
            a0 += hval * wr.x; a1 += hval * wr.y; a2 += hval * wr.z; a3 += hval * wr.w;
        }
    }
    float4 bb = *(const float4*)&b1[l * 4];
    float4 w  = *(const float4*)&W2[l * 4];
    float h0 = fmaxf(a0 + bb.x, 0.f);
    float h1 = fmaxf(a1 + bb.y, 0.f);
    float h2 = fmaxf(a2 + bb.z, 0.f);
    float h3 = fmaxf(a3 + bb.w, 0.f);

    float p = h0 * w.x + h1 * w.y + h2 * w.z + h3 * w.w;
    p += __shfl_xor(p, 1);
    p += __shfl_xor(p, 2);
    p += __shfl_xor(p, 4);
    p += __shfl_xor(p, 8);

    if (l == 0) {
        float logit = p + b2[0];
        float u0 = u[2 * e];
        float u1 = u[2 * e + 1];
        float g0 = -logf(-logf(u0));
        float g1 = -logf(-logf(u1));
        out[e]      = (logit + g1 > g0) ? 1.0f : 0.0f;
        out[NE + e] = logit;
    }
}

extern "C" void kernel_launch(void* const* d_in, const int* in_sizes, int n_in,
                              void* d_out, int out_size, void* d_ws, size_t ws_size,
                              hipStream_t stream)
{
    const float* h  = (const float*)d_in[0];
    const float* W1 = (const float*)d_in[1];
    const float* b1 = (const float*)d_in[2];
    const float* W2 = (const float*)d_in[3];
    const float* b2 = (const float*)d_in[4];
    const float* u  = (const float*)d_in[5];
    const int*   ei = (const int*)d_in[6];
    float* out = (float*)d_out;

    const size_t need = (size_t)NN * 128 * sizeof(float);   // 51.2 MB
    if (ws_size >= need) {
        float* AB = (float*)d_ws;
        int nblocks = (NN + 127) / 128;                     // 782
        node_proj<<<nblocks, 256, 0, stream>>>(h, W1, b1, AB, NN);
        edge_sample<<<NE / 16, 256, 0, stream>>>(AB, W2, b2, u, ei, out);
    } else {
        edge_direct<<<NE / 16, 256, 0, stream>>>(h, W1, b1, W2, b2, u, ei, out);
    }
}

// Round 3
// 97.156 us; speedup vs baseline: 2.0535x; 2.0535x over previous
//
#include <hip/hip_runtime.h>
#include <math.h>

#define NN 100000
#define NE 500000

// ---------------------------------------------------------------------------
// Kernel 1: per-node projection.
//   AB[n][0:64]   = h[n] @ W1[0:128, :]   + b1      (source-role, b1 folded)
//   AB[n][64:128] = h[n] @ W1[128:256, :]           (target-role)
// Treated as one GEMM: M=100000, K=128, Nout=128 with merged weight
//   Wc[k][j] = (j<64) ? W1[k][j] : W1[128+k][j-64]
// 256 threads/block, 128 nodes/block, per-lane 8 nodes x 8 outputs.
// K-chunk = 32  ->  LDS = 16KB (W) + 18KB (h) = 34KB -> 4 blocks/CU by LDS.
// __launch_bounds__(256,2): do NOT cap VGPR below ~92 — (256,4) forced a
// 64-VGPR cap and spilled acc[8][8] to scratch (R2: 423MB scratch writes,
// VALUBusy 11%). 92 VGPR <= 128 still permits 4 waves/SIMD at runtime.
// ---------------------------------------------------------------------------
__global__ __launch_bounds__(256, 2)
void node_proj(const float* __restrict__ h, const float* __restrict__ W1,
               const float* __restrict__ b1, float* __restrict__ AB, int nnodes)
{
    __shared__ float lw[32 * 128];     // 16 KB: 32 k-rows x 128 outputs
    __shared__ float lh[128 * 36];     // 18 KB: 128 nodes x 32 k, stride 36 (36%32==4 -> conflict-free)

    const int t   = threadIdx.x;
    const int tj  = t & 15;      // output group: j = 4*tj (A-half) and 64+4*tj (B-half)
    const int tnf = t >> 4;      // node group:  rows tnf + 16*r, r=0..7
    const int n0  = blockIdx.x * 128;

    float acc[8][8];
#pragma unroll
    for (int r = 0; r < 8; ++r)
#pragma unroll
        for (int j = 0; j < 8; ++j) acc[r][j] = 0.f;

    for (int kc = 0; kc < 4; ++kc) {
        // ---- stage Wc chunk: 32 rows x 128 outputs (1024 float4, 4/thread) ----
#pragma unroll
        for (int i = 0; i < 4; ++i) {
            int cid = t + 256 * i;        // 0..1023
            int kl  = cid >> 5;           // 0..31
            int q   = cid & 31;           // float4 index within row
            int jo  = q * 4;
            int kg  = kc * 32 + kl;
            const float* src = (jo < 64) ? (W1 + kg * 64 + jo)
                                         : (W1 + (128 + kg) * 64 + (jo - 64));
            float4 v = *(const float4*)src;
            *(float4*)&lw[kl * 128 + jo] = v;
        }
        // ---- stage h tile: 128 nodes x 32 k (1024 float4, 4/thread) ----
#pragma unroll
        for (int i = 0; i < 4; ++i) {
            int cid = t + 256 * i;        // 0..1023
            int nl  = cid >> 3;           // 0..127
            int kq  = cid & 7;            // 8 float4 per node-row chunk
            int ng  = n0 + nl;
            float4 v = make_float4(0.f, 0.f, 0.f, 0.f);
            if (ng < nnodes) v = *(const float4*)&h[ng * 128 + kc * 32 + kq * 4];
            *(float4*)&lh[nl * 36 + kq * 4] = v;
        }
        __syncthreads();

        // ---- FMA inner loop over this K-chunk (8 k4 iterations) ----
#pragma unroll
        for (int k4 = 0; k4 < 8; ++k4) {
            float hv[8][4];
#pragma unroll
            for (int r = 0; r < 8; ++r) {
                float4 x = *(const float4*)&lh[(tnf + 16 * r) * 36 + k4 * 4];
                hv[r][0] = x.x; hv[r][1] = x.y; hv[r][2] = x.z; hv[r][3] = x.w;
            }
#pragma unroll
            for (int kk = 0; kk < 4; ++kk) {
                float4 wa = *(const float4*)&lw[(k4 * 4 + kk) * 128 + tj * 4];
                float4 wb = *(const float4*)&lw[(k4 * 4 + kk) * 128 + 64 + tj * 4];
#pragma unroll
                for (int r = 0; r < 8; ++r) {
                    float hval = hv[r][kk];
                    acc[r][0] += hval * wa.x;
                    acc[r][1] += hval * wa.y;
                    acc[r][2] += hval * wa.z;
                    acc[r][3] += hval * wa.w;
                    acc[r][4] += hval * wb.x;
                    acc[r][5] += hval * wb.y;
                    acc[r][6] += hval * wb.z;
                    acc[r][7] += hval * wb.w;
                }
            }
        }
        __syncthreads();
    }

    // ---- epilogue: add b1 to the A-half, store both halves ----
    float4 bva = *(const float4*)&b1[tj * 4];
#pragma unroll
    for (int r = 0; r < 8; ++r) {
        int ng = n0 + tnf + 16 * r;
        if (ng >= nnodes) continue;
        float4 o1 = make_float4(acc[r][0] + bva.x, acc[r][1] + bva.y,
                                acc[r][2] + bva.z, acc[r][3] + bva.w);
        float4 o2 = make_float4(acc[r][4], acc[r][5], acc[r][6], acc[r][7]);
        *(float4*)&AB[ng * 128 + tj * 4]      = o1;   // A-half: outputs 4*tj..
        *(float4*)&AB[ng * 128 + 64 + tj * 4] = o2;   // B-half: outputs 64+4*tj..
    }
}

// ---------------------------------------------------------------------------
// Kernel 2: per-edge sample. 16 lanes per edge; lane l owns hid[4l..4l+3].
// hid = relu(AB[row][0:64] + AB[col][64:128])   (b1 already folded into A)
// logits = hid @ W2 + b2 ;  weight = (logits + g1 > g0) ? 1 : 0
// ---------------------------------------------------------------------------
__global__ __launch_bounds__(256)
void edge_sample(const float* __restrict__ AB, const float* __restrict__ W2,
                 const float* __restrict__ b2, const float* __restrict__ u,
                 const int* __restrict__ ei, float* __restrict__ out)
{
    int t = threadIdx.x;
    int l = t & 15;
    int e = blockIdx.x * 16 + (t >> 4);

    int row = ei[e];
    int col = ei[NE + e];

    float4 a = *(const float4*)&AB[row * 128 + l * 4];
    float4 b = *(const float4*)&AB[col * 128 + 64 + l * 4];
    float4 w = *(const float4*)&W2[l * 4];

    float h0 = fmaxf(a.x + b.x, 0.f);
    float h1 = fmaxf(a.y + b.y, 0.f);
    float h2 = fmaxf(a.z + b.z, 0.f);
    float h3 = fmaxf(a.w + b.w, 0.f);

    float p = h0 * w.x + h1 * w.y + h2 * w.z + h3 * w.w;
    p += __shfl_xor(p, 1);
    p += __shfl_xor(p, 2);
    p += __shfl_xor(p, 4);
    p += __shfl_xor(p, 8);

    if (l == 0) {
        float logit = p + b2[0];
        float u0 = u[2 * e];
        float u1 = u[2 * e + 1];
        float g0 = -logf(-logf(u0));
        float g1 = -logf(-logf(u1));
        out[e]      = (logit + g1 > g0) ? 1.0f : 0.0f;  // argmax tie -> 0
        out[NE + e] = logit;
    }
}

// ---------------------------------------------------------------------------
// Fallback (only if ws_size too small): direct per-edge compute, correct but slow.
// ---------------------------------------------------------------------------
__global__ __launch_bounds__(256)
void edge_direct(const float* __restrict__ h, const float* __restrict__ W1,
                 const float* __restrict__ b1, const float* __restrict__ W2,
                 const float* __restrict__ b2, const float* __restrict__ u,
                 const int* __restrict__ ei, float* __restrict__ out)
{
    int t = threadIdx.x;
    int l = t & 15;
    int e = blockIdx.x * 16 + (t >> 4);

    int row = ei[e];
    int col = ei[NE + e];

    float a0 = 0.f, a1 = 0.f, a2 = 0.f, a3 = 0.f;
    const float* hr = h + (size_t)row * 128;
    const float* hc = h + (size_t)col * 128;

    for (int k4 = 0; k4 < 32; ++k4) {
        float4 hv = *(const float4*)&hr[k4 * 4];
#pragma unroll
        for (int kk = 0; kk < 4; ++kk) {
            float4 wr = *(const float4*)&W1[(k4 * 4 + kk) * 64 + l * 4];
            float hval = (&hv.x)[kk];
            a0 += hval * wr.x; a1 += hval * wr.y; a2 += hval * wr.z; a3 += hval * wr.w;
        }
    }
    for (int k4 = 0; k4 < 32; ++k4) {
        float4 hv = *(const float4*)&hc[k4 * 4];
#pragma unroll
        for (int kk = 0; kk < 4; ++kk) {
            float4 wr = *(const float4*)&W1[(128 + k4 * 4 + kk) * 64 + l * 4];
            float hval = (&hv.x)[kk];
            a0 += hval * wr.x; a1 += hval * wr.y; a2 += hval * wr.z; a3 += hval * wr.w;
        }
    }
    float4 bb = *(const float4*)&b1[l * 4];
    float4 w  = *(const float4*)&W2[l * 4];
    float h0 = fmaxf(a0 + bb.x, 0.f);
    float h1 = fmaxf(a1 + bb.y, 0.f);
    float h2 = fmaxf(a2 + bb.z, 0.f);
    float h3 = fmaxf(a3 + bb.w, 0.f);

    float p = h0 * w.x + h1 * w.y + h2 * w.z + h3 * w.w;
    p += __shfl_xor(p, 1);
    p += __shfl_xor(p, 2);
    p += __shfl_xor(p, 4);
    p += __shfl_xor(p, 8);

    if (l == 0) {
        float logit = p + b2[0];
        float u0 = u[2 * e];
        float u1 = u[2 * e + 1];
        float g0 = -logf(-logf(u0));
        float g1 = -logf(-logf(u1));
        out[e]      = (logit + g1 > g0) ? 1.0f : 0.0f;
        out[NE + e] = logit;
    }
}

extern "C" void kernel_launch(void* const* d_in, const int* in_sizes, int n_in,
                              void* d_out, int out_size, void* d_ws, size_t ws_size,
                              hipStream_t stream)
{
    const float* h  = (const float*)d_in[0];
    const float* W1 = (const float*)d_in[1];
    const float* b1 = (const float*)d_in[2];
    const float* W2 = (const float*)d_in[3];
    const float* b2 = (const float*)d_in[4];
    const float* u  = (const float*)d_in[5];
    const int*   ei = (const int*)d_in[6];
    float* out = (float*)d_out;

    const size_t need = (size_t)NN * 128 * sizeof(float);   // 51.2 MB
    if (ws_size >= need) {
        float* AB = (float*)d_ws;
        int nblocks = (NN + 127) / 128;                     // 782
        node_proj<<<nblocks, 256, 0, stream>>>(h, W1, b1, AB, NN);
        edge_sample<<<NE / 16, 256, 0, stream>>>(AB, W2, b2, u, ei, out);
    } else {
        edge_direct<<<NE / 16, 256, 0, stream>>>(h, W1, b1, W2, b2, u, ei, out);
    }
}